// Round 2
// baseline (41359.906 us; speedup 1.0000x reference)
//
#include <hip/hip_runtime.h>
#include <hip/hip_bf16.h>
#include <hip/hip_cooperative_groups.h>

namespace cg = cooperative_groups;

#define UNITS 1024
#define BATCH 128
#define SEQ   512
#define LROW  1032   // LDS row stride in shorts (2064 B) — pad breaks bank aliasing

typedef short bf16x8 __attribute__((ext_vector_type(8)));
typedef float f32x4  __attribute__((ext_vector_type(4)));

// ---- fp32 <-> bf16 split helpers (RNE) ----
__device__ __forceinline__ unsigned short f2bf(float v) {
    union { float f; unsigned u; } x; x.f = v;
    unsigned r = x.u + 0x7fffu + ((x.u >> 16) & 1u);
    return (unsigned short)(r >> 16);
}
__device__ __forceinline__ float bf2f(unsigned short s) {
    union { unsigned u; float f; } x; x.u = ((unsigned)s) << 16;
    return x.f;
}
__device__ __forceinline__ float sigmf(float v) { return 1.0f / (1.0f + expf(-v)); }

// A: lane holds A[row=l&15][k=8*(l>>4)+j]; B: B[k=8*(l>>4)+j][col=l&15];
// D: D[row=4*(l>>4)+r][col=l&15]  (m89/m97-verified layouts)
__device__ __forceinline__ f32x4 mfma_bf16(bf16x8 a, bf16x8 b, f32x4 c) {
    asm("v_mfma_f32_16x16x32_bf16 %0, %1, %2, %0" : "+v"(c) : "v"(a), "v"(b));
    return c;
}

// ============ prep: transpose + dual-bf16 split of weights ============
// virtual source columns: c in [0,1024) -> Wh ; c in [1024,5120) -> gate col
// cc=c-1024, g=cc&3 (f,i,c,o), j=cc>>2  => gate-interleaved so one WG owns
// all 4 gates of its 8 h-columns.
__global__ void prep_split(const float* __restrict__ Wh,
                           const float* __restrict__ Wf,
                           const float* __restrict__ Wi,
                           const float* __restrict__ Wc,
                           const float* __restrict__ Wo,
                           unsigned short* __restrict__ WhT_hi,
                           unsigned short* __restrict__ WhT_lo,
                           unsigned short* __restrict__ WcT_hi,
                           unsigned short* __restrict__ WcT_lo)
{
    __shared__ float tile[32][33];
    const int ct = blockIdx.x;   // 0..159
    const int kt = blockIdx.y;   // 0..31
    const int tx = threadIdx.x;  // 0..31
    const int ty = threadIdx.y;  // 0..7
    const int cbase = ct * 32, kbase = kt * 32;

    #pragma unroll
    for (int i = 0; i < 4; ++i) {
        int kl = ty + i * 8;
        int k  = kbase + kl;
        int c  = cbase + tx;
        float v;
        if (c < UNITS) {
            v = Wh[k * UNITS + c];
        } else {
            int cc = c - UNITS;
            int g = cc & 3, j = cc >> 2;
            const float* W = (g == 0) ? Wf : (g == 1) ? Wi : (g == 2) ? Wc : Wo;
            v = W[k * UNITS + j];
        }
        tile[kl][tx] = v;
    }
    __syncthreads();
    #pragma unroll
    for (int i = 0; i < 4; ++i) {
        int cl = ty + i * 8;
        int c  = cbase + cl;
        int k  = kbase + tx;
        float v = tile[tx][cl];
        unsigned short hi = f2bf(v);
        unsigned short lo = f2bf(v - bf2f(hi));
        if (c < UNITS) {
            WhT_hi[c * UNITS + k] = hi;
            WhT_lo[c * UNITS + k] = lo;
        } else {
            int cc = c - UNITS;
            WcT_hi[cc * UNITS + k] = hi;
            WcT_lo[cc * UNITS + k] = lo;
        }
    }
}

// ============ persistent LSTM loop, cooperative ============
// grid 256 x 256thr, 1 WG/CU. Per step:
//   phase1: inp = h@Wh + E[x_t] + b   (256 WGs: 4 Mtiles(32) x 64 coltiles(16);
//           waves: mt=wave&1, K-half=wave>>1, LDS reduce)
//   phase2: G = inp@Wcat (interleaved gates); per-WG tile 64x32 gate-cols,
//           wave owns 16 rows full-K; epilogue does LSTM update + y write.
__global__ void __launch_bounds__(256, 1)
lstm_persistent(const int* __restrict__ x, const float* __restrict__ E,
                const float* __restrict__ bvec,
                const float* __restrict__ bfv, const float* __restrict__ biv,
                const float* __restrict__ bcv, const float* __restrict__ bov,
                const unsigned short* __restrict__ WhT_hi, const unsigned short* __restrict__ WhT_lo,
                const unsigned short* __restrict__ WcT_hi, const unsigned short* __restrict__ WcT_lo,
                float* __restrict__ h, unsigned short* __restrict__ h_hi, unsigned short* __restrict__ h_lo,
                unsigned short* __restrict__ inp_hi, unsigned short* __restrict__ inp_lo,
                float* __restrict__ out)
{
    __shared__ unsigned short lbh[32 * LROW];              // 64.5 KiB gate-W hi (padded rows)
    __shared__ unsigned short lbl[32 * LROW];              // 64.5 KiB gate-W lo
    __shared__ __align__(16) float sc[4][16][36];          // reduce/epilogue scratch

    cg::grid_group grid = cg::this_grid();

    const int wg = blockIdx.x, tid = threadIdx.x;
    const int wave = tid >> 6, lane = tid & 63;
    const int l16 = lane & 15, lk = lane >> 4;

    // phase-2 tile
    const int m2  = wg >> 7;          // 0..1 (64-row half)
    const int ct2 = wg & 127;         // 0..127 (32 gate-cols = 8 h-cols x 4 gates)
    const int cb2 = ct2 * 32;
    const int R2  = m2 * 64 + wave * 16;

    // phase-1 tile
    const int m1  = wg >> 6;          // 0..3 (32-row quarter)
    const int cb1 = (wg & 63) * 16;
    const int R1  = m1 * 32 + (wave & 1) * 16;
    const int kh1 = (wave >> 1) * 512;

    // ---- stage gate-weight tile into LDS (padded row stride 2064 B) ----
    {
        const uint4* srcH = (const uint4*)(WcT_hi + (size_t)cb2 * UNITS);
        const uint4* srcL = (const uint4*)(WcT_lo + (size_t)cb2 * UNITS);
        uint4* dH = (uint4*)lbh; uint4* dL = (uint4*)lbl;
        for (int idx = tid; idx < 32 * 128; idx += 256) {
            int r = idx >> 7, o = idx & 127;   // row, 16B-chunk within row
            dH[r * 129 + o] = srcH[idx];
            dL[r * 129 + o] = srcL[idx];
        }
    }
    // ---- zero the recurrent state ----
    for (int i = wg * 256 + tid; i < BATCH * UNITS; i += 256 * 256) {
        h[i] = 0.0f; h_hi[i] = 0; h_lo[i] = 0;
    }
    grid.sync();

    #pragma unroll 1
    for (int t = 0; t < SEQ; ++t) {
        // ================= phase 1: inp = h@Wh + E[x_t] + b =================
        {
            f32x4 a0 = {0,0,0,0}, a1 = {0,0,0,0}, a2 = {0,0,0,0};
            const unsigned short* pah = h_hi  + (R1 + l16) * UNITS + kh1 + lk * 8;
            const unsigned short* pal = h_lo  + (R1 + l16) * UNITS + kh1 + lk * 8;
            const unsigned short* pbh = WhT_hi + (cb1 + l16) * UNITS + kh1 + lk * 8;
            const unsigned short* pbl = WhT_lo + (cb1 + l16) * UNITS + kh1 + lk * 8;
            asm volatile("s_nop 3");   // VALU acc-init -> MFMA SrcC hazard guard
            #pragma unroll 4
            for (int ks = 0; ks < 16; ++ks) {
                bf16x8 ah = *(const bf16x8*)pah; pah += 32;
                bf16x8 al = *(const bf16x8*)pal; pal += 32;
                bf16x8 bh = *(const bf16x8*)pbh; pbh += 32;
                bf16x8 bl = *(const bf16x8*)pbl; pbl += 32;
                a0 = mfma_bf16(ah, bh, a0);
                a1 = mfma_bf16(ah, bl, a1);
                a2 = mfma_bf16(al, bh, a2);
            }
            asm volatile("s_nop 7\n\ts_nop 7" : "+v"(a0), "+v"(a1), "+v"(a2));
            #pragma unroll
            for (int r = 0; r < 4; ++r)
                sc[wave][lk * 4 + r][l16] = a0[r] + a1[r] + a2[r];
        }
        __syncthreads();
        if (wave < 2) {   // waves 0,1: reduce K-halves, add E[x]+b, split, store
            const int Rb = m1 * 32 + wave * 16;
            #pragma unroll
            for (int it = 0; it < 4; ++it) {
                int idx = it * 64 + lane;
                int rr = idx >> 4, cc = idx & 15;
                float v = sc[wave][rr][cc] + sc[wave + 2][rr][cc];
                int row = Rb + rr, col = cb1 + cc;
                int xv = x[row * SEQ + t];
                v += E[(size_t)xv * UNITS + col] + bvec[col];
                unsigned short hi = f2bf(v);
                unsigned short lo = f2bf(v - bf2f(hi));
                inp_hi[row * UNITS + col] = hi;
                inp_lo[row * UNITS + col] = lo;
            }
        }
        grid.sync();

        // ============ phase 2: gates = inp@Wcat ; LSTM update ; emit y ============
        {
            f32x4 c0a={0,0,0,0}, c0b={0,0,0,0}, c0c={0,0,0,0};
            f32x4 c1a={0,0,0,0}, c1b={0,0,0,0}, c1c={0,0,0,0};
            const unsigned short* pah = inp_hi + (R2 + l16) * UNITS + lk * 8;
            const unsigned short* pal = inp_lo + (R2 + l16) * UNITS + lk * 8;
            const int b0 = l16 * 2064 + lk * 16;          // row l16, k-chunk lk
            const int b1 = (16 + l16) * 2064 + lk * 16;   // row 16+l16
            const char* qh = (const char*)lbh;
            const char* ql = (const char*)lbl;
            asm volatile("s_nop 3");   // VALU acc-init -> MFMA SrcC hazard guard
            #pragma unroll 2
            for (int ks = 0; ks < 32; ++ks) {
                bf16x8 ah  = *(const bf16x8*)pah; pah += 32;
                bf16x8 al  = *(const bf16x8*)pal; pal += 32;
                bf16x8 b0h = *(const bf16x8*)(qh + b0 + ks * 64);
                bf16x8 b0l = *(const bf16x8*)(ql + b0 + ks * 64);
                bf16x8 b1h = *(const bf16x8*)(qh + b1 + ks * 64);
                bf16x8 b1l = *(const bf16x8*)(ql + b1 + ks * 64);
                c0a = mfma_bf16(ah, b0h, c0a);
                c1a = mfma_bf16(ah, b1h, c1a);
                c0b = mfma_bf16(ah, b0l, c0b);
                c1b = mfma_bf16(ah, b1l, c1b);
                c0c = mfma_bf16(al, b0h, c0c);
                c1c = mfma_bf16(al, b1h, c1c);
            }
            asm volatile("s_nop 7\n\ts_nop 7"
                         : "+v"(c0a), "+v"(c0b), "+v"(c0c), "+v"(c1a), "+v"(c1b), "+v"(c1c));
            #pragma unroll
            for (int r = 0; r < 4; ++r) {
                sc[wave][lk * 4 + r][l16]      = c0a[r] + c0b[r] + c0c[r];
                sc[wave][lk * 4 + r][16 + l16] = c1a[r] + c1b[r] + c1c[r];
            }
        }
        __syncthreads();
        {
            const int jb = ct2 * 8;
            #pragma unroll
            for (int it = 0; it < 2; ++it) {
                int idx = it * 64 + lane;          // 16 rows x 8 h-cols per wave
                int rr = idx >> 3, jj = idx & 7;
                f32x4 g4 = *(const f32x4*)&sc[wave][rr][jj * 4];   // f,i,c,o
                int col = jb + jj;
                int row = R2 + rr;
                float pf = g4[0] + bfv[col];
                float pi = g4[1] + biv[col];
                float pc = g4[2] + bcv[col];
                float po = g4[3] + bov[col];
                float hold = h[row * UNITS + col];
                float ff = sigmf(pf), ii = sigmf(pi), cv = tanhf(pc), oo = sigmf(po);
                float h1 = ff * hold + ii * cv;
                float y  = oo * tanhf(h1);
                h[row * UNITS + col] = h1;
                unsigned short hh = f2bf(h1);
                h_hi[row * UNITS + col] = hh;
                h_lo[row * UNITS + col] = f2bf(h1 - bf2f(hh));
                out[((size_t)row * SEQ + t) * UNITS + col] = y;
            }
        }
        grid.sync();
    }
}

extern "C" void kernel_launch(void* const* d_in, const int* in_sizes, int n_in,
                              void* d_out, int out_size, void* d_ws, size_t ws_size,
                              hipStream_t stream)
{
    const int*   x    = (const int*)d_in[0];
    const float* E    = (const float*)d_in[1];
    const float* Wh   = (const float*)d_in[2];
    const float* bvec = (const float*)d_in[3];
    const float* Wf   = (const float*)d_in[4];
    const float* bfv  = (const float*)d_in[5];
    const float* Wi   = (const float*)d_in[6];
    const float* biv  = (const float*)d_in[7];
    const float* Wc   = (const float*)d_in[8];
    const float* bcv  = (const float*)d_in[9];
    const float* Wo   = (const float*)d_in[10];
    const float* bov  = (const float*)d_in[11];
    float* out = (float*)d_out;

    char* w = (char*)d_ws;
    const size_t SZW = (size_t)UNITS * UNITS * 2;       // one 1024x1024 bf16 plane
    unsigned short* WhT_hi = (unsigned short*)(w);
    unsigned short* WhT_lo = (unsigned short*)(w + SZW);
    unsigned short* WcT_hi = (unsigned short*)(w + 2 * SZW);
    unsigned short* WcT_lo = (unsigned short*)(w + 6 * SZW);
    char* s = w + 10 * SZW;                             // 20 MiB used so far
    float*          hbuf = (float*)(s);                                  // 512 KiB
    unsigned short* hhi  = (unsigned short*)(s + (size_t)BATCH*UNITS*4);
    unsigned short* hlo  = (unsigned short*)(s + (size_t)BATCH*UNITS*6);
    unsigned short* ihi  = (unsigned short*)(s + (size_t)BATCH*UNITS*8);
    unsigned short* ilo  = (unsigned short*)(s + (size_t)BATCH*UNITS*10);
    // total ws usage ~= 21.5 MiB

    prep_split<<<dim3(160, 32), dim3(32, 8), 0, stream>>>(
        Wh, Wf, Wi, Wc, Wo, WhT_hi, WhT_lo, WcT_hi, WcT_lo);

    void* args[] = {
        (void*)&x, (void*)&E, (void*)&bvec, (void*)&bfv, (void*)&biv, (void*)&bcv, (void*)&bov,
        (void*)&WhT_hi, (void*)&WhT_lo, (void*)&WcT_hi, (void*)&WcT_lo,
        (void*)&hbuf, (void*)&hhi, (void*)&hlo, (void*)&ihi, (void*)&ilo, (void*)&out
    };
    hipLaunchCooperativeKernel(reinterpret_cast<void*>(lstm_persistent),
                               dim3(256), dim3(256), args, 0, stream);
}